// Round 1
// baseline (229.232 us; speedup 1.0000x reference)
//
#include <hip/hip_runtime.h>
#include <hip/hip_bf16.h>

typedef __attribute__((ext_vector_type(8))) short short8;
typedef __attribute__((ext_vector_type(4))) float f32x4;
typedef unsigned short ushort_t;

__device__ __forceinline__ ushort_t f2bf(float f) {
    union { __hip_bfloat16 h; ushort_t u; } c;
    c.h = __float2bfloat16(f);
    return c.u;
}

// ---------------- convert x fp32 -> bf16 ----------------
__global__ __launch_bounds__(256) void k_convert_x(const float* __restrict__ x,
                                                   ushort_t* __restrict__ xb) {
    size_t idx = ((size_t)blockIdx.x * 256 + threadIdx.x) * 8;
    float4 a = *(const float4*)(x + idx);
    float4 b = *(const float4*)(x + idx + 4);
    short8 o;
    o[0] = (short)f2bf(a.x); o[1] = (short)f2bf(a.y);
    o[2] = (short)f2bf(a.z); o[3] = (short)f2bf(a.w);
    o[4] = (short)f2bf(b.x); o[5] = (short)f2bf(b.y);
    o[6] = (short)f2bf(b.z); o[7] = (short)f2bf(b.w);
    *(short8*)(xb + idx) = o;
}

// ---------------- transpose W fp32 [d][e] -> bf16 Wt [e][d], 3 weights -------
__global__ __launch_bounds__(256) void k_transpose_w(const float* __restrict__ W0,
                                                     const float* __restrict__ W1,
                                                     const float* __restrict__ W2,
                                                     ushort_t* __restrict__ Wt) {
    const float* W = (blockIdx.z == 0) ? W0 : (blockIdx.z == 1) ? W1 : W2;
    ushort_t* out = Wt + (size_t)blockIdx.z * 1024 * 1024;
    __shared__ float tile[32][33];
    int tx = threadIdx.x, ty = threadIdx.y;            // 32 x 8
    int d0 = blockIdx.y * 32, e0 = blockIdx.x * 32;
#pragma unroll
    for (int i = 0; i < 32; i += 8)
        tile[ty + i][tx] = W[(size_t)(d0 + ty + i) * 1024 + e0 + tx];
    __syncthreads();
#pragma unroll
    for (int i = 0; i < 32; i += 8)
        out[(size_t)(e0 + ty + i) * 1024 + d0 + tx] = f2bf(tile[tx][ty + i]);
}

// ---------------- transpose V bf16 [b][j][e] -> Vt [b][e][j] ----------------
__global__ __launch_bounds__(256) void k_transpose_v(const ushort_t* __restrict__ V,
                                                     ushort_t* __restrict__ Vt) {
    int b = blockIdx.z;
    const ushort_t* in = V + (size_t)b * 2048 * 1024;
    ushort_t* out = Vt + (size_t)b * 1024 * 2048;
    __shared__ ushort_t tile[32][33];
    int tx = threadIdx.x, ty = threadIdx.y;            // 32 x 8
    int e0 = blockIdx.x * 32, j0 = blockIdx.y * 32;
#pragma unroll
    for (int i = 0; i < 32; i += 8)
        tile[ty + i][tx] = in[(size_t)(j0 + ty + i) * 1024 + e0 + tx];
    __syncthreads();
#pragma unroll
    for (int i = 0; i < 32; i += 8)
        out[(size_t)(e0 + ty + i) * 2048 + j0 + tx] = tile[tx][ty + i];
}

// ---------------- GEMM: C[M][N] = A[M][K] * B[N][K]^T, bf16 in, 128x128 tile -
// MODE 0: proj  A=xb[8192][1024]      B=Wt[z][1024][1024]  C=QKV bf16
// MODE 1: qk    A=Q[b][2048][1024]    B=K[b][2048][1024]   C=scores fp32 (*1/32, causal)
// MODE 2: pv    A=P bf16 lda=4096     B=Vt[b][1024][2048]  C=out fp32, K-range causal
template <int MODE>
__global__ __launch_bounds__(256) void k_gemm(const ushort_t* __restrict__ Abase,
                                              const ushort_t* __restrict__ Bbase,
                                              void* __restrict__ Cbase) {
    const int bm = blockIdx.x, bn = blockIdx.y, bz = blockIdx.z;

    const ushort_t* A;
    const ushort_t* B;
    int lda, ldb, nk;
    if constexpr (MODE == 0) {
        A = Abase; lda = 1024;
        B = Bbase + (size_t)bz * 1024 * 1024; ldb = 1024;
        nk = 32;
    } else if constexpr (MODE == 1) {
        if (bn > bm) return;  // fully-masked causal tile
        A = Abase + (size_t)bz * 2048 * 1024; lda = 1024;
        B = Bbase + (size_t)bz * 2048 * 1024; ldb = 1024;
        nk = 32;
    } else {
        A = Abase + (size_t)bz * 2048 * 4096; lda = 4096;
        B = Bbase + (size_t)bz * 1024 * 2048; ldb = 2048;
        nk = (bm + 1) * 4;  // causal K truncation: j <= bm*128+127
    }

    __shared__ ushort_t As[128 * 40];
    __shared__ ushort_t Bs[128 * 40];

    const int tid = threadIdx.x;
    const int ar = tid >> 1;
    const int ac = (tid & 1) << 4;      // 0 or 16

    const int l = tid & 63, wid = tid >> 6;
    const int wr = (wid >> 1) * 64, wc = (wid & 1) * 64;
    const int lr = l & 15, kc = (l >> 4) * 8;

    f32x4 zero = {0.f, 0.f, 0.f, 0.f};
    f32x4 acc[4][4];
#pragma unroll
    for (int m = 0; m < 4; ++m)
#pragma unroll
        for (int n = 0; n < 4; ++n) acc[m][n] = zero;

    for (int ks = 0; ks < nk; ++ks) {
        const ushort_t* ap = A + (size_t)(bm * 128 + ar) * lda + ks * 32 + ac;
        const ushort_t* bp = B + (size_t)(bn * 128 + ar) * ldb + ks * 32 + ac;
        short8 av0 = *(const short8*)ap;
        short8 av1 = *(const short8*)(ap + 8);
        short8 bv0 = *(const short8*)bp;
        short8 bv1 = *(const short8*)(bp + 8);
        __syncthreads();
        *(short8*)&As[ar * 40 + ac] = av0;
        *(short8*)&As[ar * 40 + ac + 8] = av1;
        *(short8*)&Bs[ar * 40 + ac] = bv0;
        *(short8*)&Bs[ar * 40 + ac + 8] = bv1;
        __syncthreads();

        short8 a[4], b[4];
#pragma unroll
        for (int m = 0; m < 4; ++m)
            a[m] = *(const short8*)&As[(wr + m * 16 + lr) * 40 + kc];
#pragma unroll
        for (int n = 0; n < 4; ++n)
            b[n] = *(const short8*)&Bs[(wc + n * 16 + lr) * 40 + kc];
#pragma unroll
        for (int m = 0; m < 4; ++m)
#pragma unroll
            for (int n = 0; n < 4; ++n)
                acc[m][n] = __builtin_amdgcn_mfma_f32_16x16x32_bf16(a[m], b[n], acc[m][n], 0, 0, 0);
    }

    // epilogue
    const int rbase = (l >> 4) * 4;
    const int cbase = l & 15;
#pragma unroll
    for (int m = 0; m < 4; ++m) {
#pragma unroll
        for (int n = 0; n < 4; ++n) {
            int row0 = wr + m * 16 + rbase;
            int col = wc + n * 16 + cbase;
            int gcol = bn * 128 + col;
#pragma unroll
            for (int r = 0; r < 4; ++r) {
                int grow = bm * 128 + row0 + r;
                float v = acc[m][n][r];
                if constexpr (MODE == 0) {
                    ushort_t* C = (ushort_t*)Cbase + (size_t)bz * 8192 * 1024;
                    C[(size_t)grow * 1024 + gcol] = f2bf(v);
                } else if constexpr (MODE == 1) {
                    float* C = (float*)Cbase + (size_t)bz * 2048 * 2048;
                    if (gcol <= grow) C[(size_t)grow * 2048 + gcol] = v * 0.03125f;
                } else {
                    float* C = (float*)Cbase + (size_t)bz * 2048 * 1024;
                    C[(size_t)grow * 1024 + gcol] = v;
                }
            }
        }
    }
}

// ---------------- row softmax: fp32 scores row -> normalized bf16 P in place -
__global__ __launch_bounds__(256) void k_softmax(float* __restrict__ scores) {
    const int t = blockIdx.x;        // global row 0..8191
    const int i = t & 2047;          // row within batch (causal limit)
    float* row = scores + (size_t)t * 2048;
    const int tid = threadIdx.x;
    const int j0 = tid * 8;

    float4 f0 = *(const float4*)(row + j0);
    float4 f1 = *(const float4*)(row + j0 + 4);
    float v[8] = {f0.x, f0.y, f0.z, f0.w, f1.x, f1.y, f1.z, f1.w};

    float m = -3.0e38f;
#pragma unroll
    for (int e = 0; e < 8; ++e)
        if (j0 + e <= i) m = fmaxf(m, v[e]);
#pragma unroll
    for (int off = 32; off > 0; off >>= 1) m = fmaxf(m, __shfl_down(m, off, 64));

    __shared__ float redm[4];
    __shared__ float reds[4];
    const int lane = tid & 63, wid = tid >> 6;
    if (lane == 0) redm[wid] = m;
    __syncthreads();
    m = fmaxf(fmaxf(redm[0], redm[1]), fmaxf(redm[2], redm[3]));

    float p[8];
    float s = 0.f;
#pragma unroll
    for (int e = 0; e < 8; ++e) {
        p[e] = (j0 + e <= i) ? __expf(v[e] - m) : 0.f;
        s += p[e];
    }
#pragma unroll
    for (int off = 32; off > 0; off >>= 1) s += __shfl_down(s, off, 64);
    if (lane == 0) reds[wid] = s;
    __syncthreads();
    s = reds[0] + reds[1] + reds[2] + reds[3];
    float inv = 1.f / s;

    short8 o;
#pragma unroll
    for (int e = 0; e < 8; ++e) o[e] = (short)f2bf(p[e] * inv);
    *(short8*)((ushort_t*)row + j0) = o;   // bf16 row, stride 4096 elems
}

extern "C" void kernel_launch(void* const* d_in, const int* in_sizes, int n_in,
                              void* d_out, int out_size, void* d_ws, size_t ws_size,
                              hipStream_t stream) {
    const float* x  = (const float*)d_in[0];
    const float* Wq = (const float*)d_in[1];
    const float* Wk = (const float*)d_in[2];
    const float* Wv = (const float*)d_in[3];

    char* ws = (char*)d_ws;
    ushort_t* xb     = (ushort_t*)(ws);                 // 16 MB
    ushort_t* Wt     = (ushort_t*)(ws + 16777216);      // 6 MB  [3][1024][1024]
    ushort_t* QKV    = (ushort_t*)(ws + 23068672);      // 48 MB [3][8192][1024]
    ushort_t* Vt     = (ushort_t*)(ws + 73400320);      // 16 MB [4][1024][2048]
    float*    scores = (float*)   (ws + 90177536);      // 64 MB [4][2048][2048] fp32 / P bf16

    ushort_t* Q = QKV;
    ushort_t* K = QKV + (size_t)8192 * 1024;
    ushort_t* V = QKV + (size_t)2 * 8192 * 1024;

    k_convert_x<<<4096, 256, 0, stream>>>(x, xb);
    k_transpose_w<<<dim3(32, 32, 3), dim3(32, 8), 0, stream>>>(Wq, Wk, Wv, Wt);
    k_gemm<0><<<dim3(64, 8, 3), 256, 0, stream>>>(xb, Wt, QKV);
    k_transpose_v<<<dim3(32, 64, 4), dim3(32, 8), 0, stream>>>(V, Vt);
    k_gemm<1><<<dim3(16, 16, 4), 256, 0, stream>>>(Q, K, scores);
    k_softmax<<<8192, 256, 0, stream>>>(scores);
    k_gemm<2><<<dim3(16, 8, 4), 256, 0, stream>>>((const ushort_t*)scores, Vt, (float*)d_out);
}

// Round 2
// 205.725 us; speedup vs baseline: 1.1143x; 1.1143x over previous
//
#include <hip/hip_runtime.h>
#include <hip/hip_bf16.h>

typedef __attribute__((ext_vector_type(8))) short short8;
typedef __attribute__((ext_vector_type(4))) float f32x4;
typedef unsigned short ushort_t;

__device__ __forceinline__ ushort_t f2bf(float f) {
    union { __hip_bfloat16 h; ushort_t u; } c;
    c.h = __float2bfloat16(f);
    return c.u;
}

__device__ __forceinline__ void gload16(const ushort_t* g, ushort_t* l) {
    __builtin_amdgcn_global_load_lds(
        (const __attribute__((address_space(1))) void*)g,
        (__attribute__((address_space(3))) void*)l, 16, 0, 0);
}

// ---------------- convert x fp32 -> bf16 ----------------
__global__ __launch_bounds__(256) void k_convert_x(const float* __restrict__ x,
                                                   ushort_t* __restrict__ xb) {
    size_t idx = ((size_t)blockIdx.x * 256 + threadIdx.x) * 8;
    float4 a = *(const float4*)(x + idx);
    float4 b = *(const float4*)(x + idx + 4);
    short8 o;
    o[0] = (short)f2bf(a.x); o[1] = (short)f2bf(a.y);
    o[2] = (short)f2bf(a.z); o[3] = (short)f2bf(a.w);
    o[4] = (short)f2bf(b.x); o[5] = (short)f2bf(b.y);
    o[6] = (short)f2bf(b.z); o[7] = (short)f2bf(b.w);
    *(short8*)(xb + idx) = o;
}

// ---------------- transpose W fp32 [d][e] -> bf16 Wt [e][d], 3 weights -------
__global__ __launch_bounds__(256) void k_transpose_w(const float* __restrict__ W0,
                                                     const float* __restrict__ W1,
                                                     const float* __restrict__ W2,
                                                     ushort_t* __restrict__ Wt) {
    const float* W = (blockIdx.z == 0) ? W0 : (blockIdx.z == 1) ? W1 : W2;
    ushort_t* out = Wt + (size_t)blockIdx.z * 1024 * 1024;
    __shared__ float tile[32][33];
    int tx = threadIdx.x, ty = threadIdx.y;            // 32 x 8
    int d0 = blockIdx.y * 32, e0 = blockIdx.x * 32;
#pragma unroll
    for (int i = 0; i < 32; i += 8)
        tile[ty + i][tx] = W[(size_t)(d0 + ty + i) * 1024 + e0 + tx];
    __syncthreads();
#pragma unroll
    for (int i = 0; i < 32; i += 8)
        out[(size_t)(e0 + ty + i) * 1024 + d0 + tx] = f2bf(tile[tx][ty + i]);
}

// ---------------- transpose V bf16 [b][j][e] -> Vt [b][e][j] ----------------
__global__ __launch_bounds__(256) void k_transpose_v(const ushort_t* __restrict__ V,
                                                     ushort_t* __restrict__ Vt) {
    int b = blockIdx.z;
    const ushort_t* in = V + (size_t)b * 2048 * 1024;
    ushort_t* out = Vt + (size_t)b * 1024 * 2048;
    __shared__ ushort_t tile[32][33];
    int tx = threadIdx.x, ty = threadIdx.y;            // 32 x 8
    int e0 = blockIdx.x * 32, j0 = blockIdx.y * 32;
#pragma unroll
    for (int i = 0; i < 32; i += 8)
        tile[ty + i][tx] = in[(size_t)(j0 + ty + i) * 1024 + e0 + tx];
    __syncthreads();
#pragma unroll
    for (int i = 0; i < 32; i += 8)
        out[(size_t)(e0 + ty + i) * 2048 + j0 + tx] = tile[tx][ty + i];
}

// ---------------- GEMM: C[M][N] = A[M][K] * B[N][K]^T, bf16 in, 128x128 tile -
// m97 structure: global_load_lds width=16 staging into linear [128][32] LDS,
// 2 barriers per K-step, 16x 16x16x32 MFMA per K-step.
// MODE 0: proj  A=xb[8192][1024]      B=Wt[z][1024][1024]  C=QKV bf16
// MODE 1: qk    A=Q[b][2048][1024]    B=K[b][2048][1024]   C=scores fp32 (*1/32, causal)
// MODE 2: pv    A=P bf16 lda=4096     B=Vt[b][1024][2048]  C=out fp32, K-range causal
template <int MODE>
__global__ __launch_bounds__(256) void k_gemm(const ushort_t* __restrict__ Abase,
                                              const ushort_t* __restrict__ Bbase,
                                              void* __restrict__ Cbase) {
    const int bm = blockIdx.x, bn = blockIdx.y, bz = blockIdx.z;

    const ushort_t* A;
    const ushort_t* B;
    int lda, ldb, nk;
    if constexpr (MODE == 0) {
        A = Abase; lda = 1024;
        B = Bbase + (size_t)bz * 1024 * 1024; ldb = 1024;
        nk = 32;
    } else if constexpr (MODE == 1) {
        if (bn > bm) return;  // fully-masked causal tile
        A = Abase + (size_t)bz * 2048 * 1024; lda = 1024;
        B = Bbase + (size_t)bz * 2048 * 1024; ldb = 1024;
        nk = 32;
    } else {
        A = Abase + (size_t)bz * 2048 * 4096; lda = 4096;
        B = Bbase + (size_t)bz * 1024 * 2048; ldb = 2048;
        nk = (bm + 1) * 4;  // causal K truncation: j <= bm*128+127
    }

    __shared__ ushort_t As[128 * 32];   // linear: row*32 + k (gload_lds needs linear)
    __shared__ ushort_t Bs[128 * 32];

    const int tid = threadIdx.x;
    const int l = tid & 63, wid = tid >> 6;
    const int wr = (wid >> 1) * 64, wc = (wid & 1) * 64;
    const int lr = l & 15, kc = (l >> 4) * 8;

    // staging map: LDS elem offset = chunk*2048 + tid*8  (byte = chunk*4096 + tid*16)
    //   -> row = chunk*64 + tid/4, kbase = (tid&3)*8
    const int srow = tid >> 2, skb = (tid & 3) * 8;
    const ushort_t* ag = A + (size_t)(bm * 128 + srow) * lda + skb;
    const ushort_t* bg = B + (size_t)(bn * 128 + srow) * ldb + skb;
    const size_t a64 = (size_t)64 * lda, b64 = (size_t)64 * ldb;
    ushort_t* al = As + tid * 8;
    ushort_t* bl = Bs + tid * 8;

    f32x4 zero = {0.f, 0.f, 0.f, 0.f};
    f32x4 acc[4][4];
#pragma unroll
    for (int m = 0; m < 4; ++m)
#pragma unroll
        for (int n = 0; n < 4; ++n) acc[m][n] = zero;

    for (int ks = 0; ks < nk; ++ks) {
        __syncthreads();   // previous iter's LDS reads complete
        gload16(ag, al);
        gload16(ag + a64, al + 2048);
        gload16(bg, bl);
        gload16(bg + b64, bl + 2048);
        ag += 32; bg += 32;
        __syncthreads();   // staged data visible (vmcnt drained by compiler)

        short8 a[4], b[4];
#pragma unroll
        for (int m = 0; m < 4; ++m)
            a[m] = *(const short8*)&As[(wr + m * 16 + lr) * 32 + kc];
#pragma unroll
        for (int n = 0; n < 4; ++n)
            b[n] = *(const short8*)&Bs[(wc + n * 16 + lr) * 32 + kc];
#pragma unroll
        for (int m = 0; m < 4; ++m)
#pragma unroll
            for (int n = 0; n < 4; ++n)
                acc[m][n] = __builtin_amdgcn_mfma_f32_16x16x32_bf16(a[m], b[n], acc[m][n], 0, 0, 0);
    }

    // epilogue
    const int rbase = (l >> 4) * 4;
    const int cbase = l & 15;
#pragma unroll
    for (int m = 0; m < 4; ++m) {
#pragma unroll
        for (int n = 0; n < 4; ++n) {
            int row0 = wr + m * 16 + rbase;
            int col = wc + n * 16 + cbase;
            int gcol = bn * 128 + col;
#pragma unroll
            for (int r = 0; r < 4; ++r) {
                int grow = bm * 128 + row0 + r;
                float v = acc[m][n][r];
                if constexpr (MODE == 0) {
                    ushort_t* C = (ushort_t*)Cbase + (size_t)bz * 8192 * 1024;
                    C[(size_t)grow * 1024 + gcol] = f2bf(v);
                } else if constexpr (MODE == 1) {
                    float* C = (float*)Cbase + (size_t)bz * 2048 * 2048;
                    if (gcol <= grow) C[(size_t)grow * 2048 + gcol] = v * 0.03125f;
                } else {
                    float* C = (float*)Cbase + (size_t)bz * 2048 * 1024;
                    C[(size_t)grow * 1024 + gcol] = v;
                }
            }
        }
    }
}

// ---------------- row softmax: fp32 scores row -> normalized bf16 P in place -
__global__ __launch_bounds__(256) void k_softmax(float* __restrict__ scores) {
    const int t = blockIdx.x;        // global row 0..8191
    const int i = t & 2047;          // row within batch (causal limit)
    float* row = scores + (size_t)t * 2048;
    const int tid = threadIdx.x;
    const int j0 = tid * 8;

    float4 f0 = *(const float4*)(row + j0);
    float4 f1 = *(const float4*)(row + j0 + 4);
    float v[8] = {f0.x, f0.y, f0.z, f0.w, f1.x, f1.y, f1.z, f1.w};

    float m = -3.0e38f;
#pragma unroll
    for (int e = 0; e < 8; ++e)
        if (j0 + e <= i) m = fmaxf(m, v[e]);
#pragma unroll
    for (int off = 32; off > 0; off >>= 1) m = fmaxf(m, __shfl_down(m, off, 64));

    __shared__ float redm[4];
    __shared__ float reds[4];
    const int lane = tid & 63, wid = tid >> 6;
    if (lane == 0) redm[wid] = m;
    __syncthreads();
    m = fmaxf(fmaxf(redm[0], redm[1]), fmaxf(redm[2], redm[3]));

    float p[8];
    float s = 0.f;
#pragma unroll
    for (int e = 0; e < 8; ++e) {
        p[e] = (j0 + e <= i) ? __expf(v[e] - m) : 0.f;
        s += p[e];
    }
#pragma unroll
    for (int off = 32; off > 0; off >>= 1) s += __shfl_down(s, off, 64);
    if (lane == 0) reds[wid] = s;
    __syncthreads();
    s = reds[0] + reds[1] + reds[2] + reds[3];
    float inv = 1.f / s;

    short8 o;
#pragma unroll
    for (int e = 0; e < 8; ++e) o[e] = (short)f2bf(p[e] * inv);
    *(short8*)((ushort_t*)row + j0) = o;   // bf16 row, stride 4096 elems
}

extern "C" void kernel_launch(void* const* d_in, const int* in_sizes, int n_in,
                              void* d_out, int out_size, void* d_ws, size_t ws_size,
                              hipStream_t stream) {
    const float* x  = (const float*)d_in[0];
    const float* Wq = (const float*)d_in[1];
    const float* Wk = (const float*)d_in[2];
    const float* Wv = (const float*)d_in[3];

    char* ws = (char*)d_ws;
    ushort_t* xb     = (ushort_t*)(ws);                 // 16 MB
    ushort_t* Wt     = (ushort_t*)(ws + 16777216);      // 6 MB  [3][1024][1024]
    ushort_t* QKV    = (ushort_t*)(ws + 23068672);      // 48 MB [3][8192][1024]
    ushort_t* Vt     = (ushort_t*)(ws + 73400320);      // 16 MB [4][1024][2048]
    float*    scores = (float*)   (ws + 90177536);      // 64 MB [4][2048][2048] fp32 / P bf16

    ushort_t* Q = QKV;
    ushort_t* K = QKV + (size_t)8192 * 1024;
    ushort_t* V = QKV + (size_t)2 * 8192 * 1024;

    k_convert_x<<<4096, 256, 0, stream>>>(x, xb);
    k_transpose_w<<<dim3(32, 32, 3), dim3(32, 8), 0, stream>>>(Wq, Wk, Wv, Wt);
    k_gemm<0><<<dim3(64, 8, 3), 256, 0, stream>>>(xb, Wt, QKV);
    k_transpose_v<<<dim3(32, 64, 4), dim3(32, 8), 0, stream>>>(V, Vt);
    k_gemm<1><<<dim3(16, 16, 4), 256, 0, stream>>>(Q, K, scores);
    k_softmax<<<8192, 256, 0, stream>>>(scores);
    k_gemm<2><<<dim3(16, 8, 4), 256, 0, stream>>>((const ushort_t*)scores, Vt, (float*)d_out);
}